// Round 11
// baseline (126.142 us; speedup 1.0000x reference)
//
#include <hip/hip_runtime.h>
#include <cstdint>
#include <cstddef>

#define N_ENT 40000
#define DDIM  128
#define BSZ   1024
#define NJT   313               // ceil(40000/128)
#define CH    7                 // j-tiles per block chunk (45 groups cover 313)
#define NGRID 768               // 6 strata x 8 XCD x 16 members; gp>=45 idle

#define AS1 __attribute__((address_space(1)))
#define AS3 __attribute__((address_space(3)))

typedef short s16x8 __attribute__((ext_vector_type(8)));
typedef float f32x4 __attribute__((ext_vector_type(4)));

// Fast hardware rsqrt: single v_rsq_f32 (~1 ulp). R21-verified: OCML rsqrtf
// expansion was ~14 µs of hidden VALU at 82M elements; frsq removed it
// (total 144->125 µs). Clamp semantics preserved: x=0 -> +inf -> fmin
// clamps; x<0 -> NaN -> v_min_f32 returns the non-NaN operand (U_CLAMP).
__device__ __forceinline__ float frsq(float x) { return __builtin_amdgcn_rsqf(x); }

// ws layout (bytes), 256-aligned:
//   0       : partials f32[768]   (per-block sums; idle blocks write 0)
//   20480   : tpart    f32[1024]
//   24576   : enorm    f32[40000]
//   184576  : cnorm    f32[2048]
//   192768  : c_bf     u16[2048*128]
//   717056  : ent_bf   u16[40000*128]  -> end 10,957,056 B
#define OFF_PART  0
#define OFF_TPART 20480
#define OFF_ENORM 24576
#define OFF_CNORM 184576
#define OFF_CBF   192768
#define OFF_EBF   717056

#define S_CLAMP 15.9423847f      // -ln(2^-23): clip(pred, eps, 1-eps) bound in fp32
#define U_CLAMP 0.159423847f     // S_CLAMP / 100  (s = 100*u)
#define LP_MAX (-1.1920929e-7f)  // ln(fl32(1-1e-7))

__device__ __forceinline__ unsigned short f2bf(float f) {
  uint32_t u = __float_as_uint(f);
  u += 0x7fffu + ((u >> 16) & 1u);   // round-to-nearest-even
  return (unsigned short)(u >> 16);
}

// Skinny prep, float4 width (16 B/lane): unchanged from R15 (verified).
__global__ __launch_bounds__(256) void prep_k(const float* __restrict__ ent,
                                              const int* __restrict__ pos_h,
                                              const int* __restrict__ pos_t,
                                              const int* __restrict__ neg_h,
                                              const float* __restrict__ rpos,
                                              const float* __restrict__ rneg,
                                              const int* __restrict__ l1_flag,
                                              unsigned short* __restrict__ ent_bf,
                                              float* __restrict__ enorm,
                                              unsigned short* __restrict__ c_bf,
                                              float* __restrict__ cnorm,
                                              float* __restrict__ tpart) {
  const int lane = threadIdx.x & 63, wv = threadIdx.x >> 6;
  const int ih = lane >> 5, il = lane & 31;      // half-index, lane-in-half
  const int blk = blockIdx.x;
  if (blk < 5000) {
    int row = blk * 8 + wv * 2 + ih;             // 0..39999
    float4 v = reinterpret_cast<const float4*>(ent + (size_t)row * DDIM)[il];
    ushort4 h4; h4.x = f2bf(v.x); h4.y = f2bf(v.y); h4.z = f2bf(v.z); h4.w = f2bf(v.w);
    reinterpret_cast<ushort4*>(ent_bf + (size_t)row * DDIM)[il] = h4;
    float sq = fmaf(v.x, v.x, fmaf(v.y, v.y, fmaf(v.z, v.z, v.w * v.w)));
    #pragma unroll
    for (int m = 1; m <= 16; m <<= 1) sq += __shfl_xor(sq, m);   // within 32-lane half
    if (il == 0) enorm[row] = sq;
  } else {
    int row = (blk - 5000) * 8 + wv * 2 + ih;    // 0..2047
    int br = row >> 10, i = row & 1023;
    int h = br ? neg_h[i] : pos_h[i];
    const float* rs = br ? rneg : rpos;
    float4 e  = reinterpret_cast<const float4*>(ent + (size_t)h * DDIM)[il];
    float4 rv = reinterpret_cast<const float4*>(rs + (size_t)i * DDIM)[il];
    float c0 = e.x + rv.x, c1 = e.y + rv.y, c2 = e.z + rv.z, c3 = e.w + rv.w;
    ushort4 h4; h4.x = f2bf(c0); h4.y = f2bf(c1); h4.z = f2bf(c2); h4.w = f2bf(c3);
    reinterpret_cast<ushort4*>(c_bf + (size_t)row * DDIM)[il] = h4;
    float sq = fmaf(c0, c0, fmaf(c1, c1, fmaf(c2, c2, c3 * c3)));
    #pragma unroll
    for (int m = 1; m <= 16; m <<= 1) sq += __shfl_xor(sq, m);
    if (il == 0) cnorm[row] = sq;
    if (br == 0) {
      int t = pos_t[i];
      float4 et = reinterpret_cast<const float4*>(ent + (size_t)t * DDIM)[il];
      float d0 = c0 - et.x, d1 = c1 - et.y, d2v = c2 - et.z, d3 = c3 - et.w;
      float d2 = fmaf(d0, d0, fmaf(d1, d1, fmaf(d2v, d2v, d3 * d3)));
      float m1 = fabsf(d0) + fabsf(d1) + fabsf(d2v) + fabsf(d3);
      #pragma unroll
      for (int m = 1; m <= 16; m <<= 1) { d2 += __shfl_xor(d2, m); m1 += __shfl_xor(m1, m); }
      if (il == 0) {
        float s = (*l1_flag) ? (100.f / fmaxf(m1, 1e-12f))
                             : (100.f * rsqrtf(fmaxf(d2, 0.f)));  // d2=0 -> inf, clamps ok
        float x  = __expf(-s);
        float L  = log1pf(x);
        float Bt = fminf(-L, LP_MAX);          // exact log(pred)
        float Ap = fmaxf(-s, -S_CLAMP);        // what main_k adds for this element
        tpart[i] = Bt - Ap;
      }
    }
  }
}

// Main, R22: HALF-K LDS split -> 3 blocks/CU, one generation. R21 ledger:
// per-tile wall ~4 µs = VALU 1.4 + MFMA 0.85 + ~45% stall; stall is the
// 2-waves/SIMD TLP floor pinned by the 66KB LDS dbuf (2 blocks/CU). Fix the
// LDS, not the wave tile (R17's thinner-wave split failed): stage each B
// tile as two 16KB K-halves ([2][128x64] u16, 32.8KB total incl s4) with
// the same full-ahead DMA overlap — STAGE(kh0,t+1) issued before kc2/kc3,
// STAGE(kh1,t+1) after the H1-free barrier, each drained >=2 MFMA clusters
// + epilogue later. 2 barriers/tile. A-frags: 64-reg residency -> avA/avB
// 2-deep dbuf (32 regs, reloaded per tile from L1-hot c_bf) to land arch
// VGPR ~155-165 -> 3 waves/SIMD; LDS 33KB -> 4 blocks/CU cap; net 3
// blocks/CU = 1.5x TLP. Grid: CH=7, gp = str*8 + c8 (all 16 members of a
// group on one XCD; gp>=45 idle) -> 768 blocks = 3x256 slots = ONE
// generation. Per-tile reduction dropped: ls accumulates across tiles,
// one partial per block (R18-validated regrouping, absmax 0.0).
// Element math identical to R21 (frsq epilogue, clamp masking).
__global__ __launch_bounds__(256) void main_k(const unsigned short* __restrict__ c_bf,
                                              const unsigned short* __restrict__ ent_bf,
                                              const float* __restrict__ cnorm,
                                              const float* __restrict__ enorm,
                                              const int* __restrict__ l1_flag,
                                              const int* __restrict__ pos_h,
                                              const int* __restrict__ neg_h,
                                              const float* __restrict__ rpos,
                                              const float* __restrict__ rneg,
                                              const float* __restrict__ ent_f32,
                                              float* __restrict__ partials) {
  __shared__ unsigned short smem[2][128 * 64];    // 32 KB: two K-half buffers
  __shared__ float s4[4];
  const int id = blockIdx.x;
  const int c8 = id & 7;
  const int q  = id >> 3;
  const int mm = q & 15;                          // member 0..15
  const int str = q >> 4;                         // stratum 0..5
  const int gp  = str * 8 + c8;                   // group 0..47 (45..47 idle)
  const int tid = threadIdx.x, lane = tid & 63, wv = tid >> 6;
  if (gp >= 45) {                                 // idle: zero partial, exit
    if (tid == 0) partials[id] = 0.f;
    return;
  }
  const int jtB = gp * CH;                        // <= 308
  const int nt = (jtB + CH <= NJT) ? CH : (NJT - jtB);
  const int branch = mm & 1;
  const int i0 = (mm >> 1) * 128;
  const int wm = wv >> 1, wn = wv & 1;            // 2x2 waves, 64x64 each
  const int r15 = lane & 15, quad = lane >> 4;

  // stage one 16KB K-half: 1024 chunks of 16B, 4/thread; swizzle c'=c^(r&7)
  // (LDS dst stays linear base+lane*16 per m104; swizzle folded into src)
#define STAGE(kh_, j0_) do {                                                   \
    _Pragma("unroll")                                                          \
    for (int i_ = 0; i_ < 4; ++i_) {                                           \
      int g_  = i_ * 256 + tid;                                                \
      int r_  = g_ >> 3;                  /* row 0..127 */                     \
      int cs_ = (g_ & 7) ^ (r_ & 7);      /* swizzled col chunk 0..7 */        \
      int jr_ = (j0_) + r_; if (jr_ >= N_ENT) jr_ = N_ENT - 1;                 \
      const unsigned short* src_ = ent_bf + (size_t)jr_ * DDIM + (kh_) * 64 + cs_ * 8; \
      __builtin_amdgcn_global_load_lds((const AS1 void*)src_,                  \
          (AS3 void*)(&smem[kh_][g_ * 8]), 16, 0, 0);                          \
    }                                                                          \
  } while (0)

  // B fragment read: global k-chunk q = kcL*4+quad of half kh; LDS chunk q^(R&7)
#define LOADBV(bv_, kh_, kcL_) do {                                            \
    _Pragma("unroll")                                                          \
    for (int tn_ = 0; tn_ < 4; ++tn_) {                                        \
      int R_ = wn * 64 + tn_ * 16 + r15;                                       \
      int c_ = ((kcL_) * 4 + quad) ^ (R_ & 7);                                 \
      bv_[tn_] = *reinterpret_cast<const s16x8*>(&smem[kh_][R_ * 64 + c_ * 8]); \
    }                                                                          \
  } while (0)

  // A fragment load (L1-hot c_bf, reloaded per tile into a 2-deep dbuf)
#define LOADA(dst_, kc_) do {                                                  \
    _Pragma("unroll")                                                          \
    for (int tm_ = 0; tm_ < 4; ++tm_)                                          \
      dst_[tm_] = *reinterpret_cast<const s16x8*>(aptr + (size_t)tm_ * 16 * DDIM + (kc_) * 32); \
  } while (0)

#define MFMA16(av_, bv_) do {                                                  \
    _Pragma("unroll")                                                          \
    for (int tm_ = 0; tm_ < 4; ++tm_)                                          \
      _Pragma("unroll")                                                        \
      for (int tn_ = 0; tn_ < 4; ++tn_)                                        \
        acc[tm_][tn_] = __builtin_amdgcn_mfma_f32_16x16x32_bf16(               \
            av_[tm_], bv_[tn_], acc[tm_][tn_], 0, 0, 0);                       \
  } while (0)

  const unsigned short* aptr =
      c_bf + ((size_t)(branch << 10) + i0 + wm * 64 + r15) * DDIM + quad * 8;

  STAGE(0, jtB * 128);                            // tile-0 kh0 in flight
  STAGE(1, jtB * 128);                            // tile-0 kh1 in flight

  s16x8 avA[4], avB[4];
  LOADA(avA, 0);                                  // kc0 frags

  float cnv[16];                                  // resident for the block
  #pragma unroll
  for (int tm = 0; tm < 4; ++tm)
    #pragma unroll
    for (int r = 0; r < 4; ++r)
      cnv[tm * 4 + r] = cnorm[(branch << 10) + i0 + wm * 64 + tm * 16 + quad * 4 + r];

  const int l1 = *l1_flag;
  const f32x4 zf = {0.f, 0.f, 0.f, 0.f};
  float ls0 = 0.f, ls1 = 0.f, ls2 = 0.f, ls3 = 0.f;   // accumulate all tiles

  __syncthreads();   // drains vmcnt: both tile-0 halves staged; avA/cnv landed

  #pragma unroll 1
  for (int t = 0; t < nt; ++t) {
    const int j0 = (jtB + t) * 128;
    const bool haveNext = (t + 1) < nt;           // block-uniform

    float en[4];                                  // consumed ~2 clusters later
    #pragma unroll
    for (int tn = 0; tn < 4; ++tn) {
      int jg = j0 + wn * 64 + tn * 16 + r15;
      en[tn] = enorm[jg < N_ENT ? jg : N_ENT - 1];
    }

    f32x4 acc[4][4];
    #pragma unroll
    for (int a = 0; a < 4; ++a)
      #pragma unroll
      for (int b = 0; b < 4; ++b) acc[a][b] = zf;

    s16x8 bv[4];
    // kc0/kc1 from H0; av dbuf rotates one cluster ahead
    LOADBV(bv, 0, 0);
    LOADA(avB, 1);
    MFMA16(avA, bv);
    LOADBV(bv, 0, 1);
    LOADA(avA, 2);
    MFMA16(avB, bv);

    __syncthreads();                              // B1: H0 free (lgkm drained)
    if (haveNext) STAGE(0, j0 + 128);             // refill H0; drains at B2

    // kc2/kc3 from H1
    LOADBV(bv, 1, 0);
    LOADA(avB, 3);
    MFMA16(avA, bv);
    LOADBV(bv, 1, 1);
    LOADA(avA, 0);                                // kc0 again (same data, next tile)
    MFMA16(avB, bv);

    __syncthreads();                              // B2: H1 free; drains STAGE(0,t+1)
    if (haveNext) STAGE(1, j0 + 128);             // refill H1; drains at next B1

    // ---- epilogue: add, fma, v_rsq, fmin, add (u-units), 4 accumulators ----
    const bool full = (j0 + 128) <= N_ENT;        // block-uniform per tile
    if (!l1) {
      #pragma unroll
      for (int tm = 0; tm < 4; ++tm) {
        if (full) {
          #pragma unroll
          for (int tn = 0; tn < 4; ++tn) {
            float e0 = en[tn];
            float u0 = frsq(fmaf(-2.f, acc[tm][tn][0], cnv[tm * 4 + 0] + e0));
            float u1 = frsq(fmaf(-2.f, acc[tm][tn][1], cnv[tm * 4 + 1] + e0));
            float u2 = frsq(fmaf(-2.f, acc[tm][tn][2], cnv[tm * 4 + 2] + e0));
            float u3 = frsq(fmaf(-2.f, acc[tm][tn][3], cnv[tm * 4 + 3] + e0));
            ls0 += fminf(u0, U_CLAMP);            // <=0/NaN -> fmin clamps
            ls1 += fminf(u1, U_CLAMP);
            ls2 += fminf(u2, U_CLAMP);
            ls3 += fminf(u3, U_CLAMP);
          }
        } else {
          #pragma unroll
          for (int tn = 0; tn < 4; ++tn) {
            int jg = j0 + wn * 64 + tn * 16 + r15;
            if (jg < N_ENT) {
              float e0 = en[tn];
              ls0 += fminf(frsq(fmaf(-2.f, acc[tm][tn][0], cnv[tm * 4 + 0] + e0)), U_CLAMP);
              ls1 += fminf(frsq(fmaf(-2.f, acc[tm][tn][1], cnv[tm * 4 + 1] + e0)), U_CLAMP);
              ls2 += fminf(frsq(fmaf(-2.f, acc[tm][tn][2], cnv[tm * 4 + 2] + e0)), U_CLAMP);
              ls3 += fminf(frsq(fmaf(-2.f, acc[tm][tn][3], cnv[tm * 4 + 3] + e0)), U_CLAMP);
            }
          }
        }
      }
    } else {
      // L1 fallback (dead with this harness's inputs): recompute on the fly.
      const float* rs = branch ? rneg : rpos;
      const int*   hb = branch ? neg_h : pos_h;
      #pragma unroll 1
      for (int tm = 0; tm < 4; ++tm) {
        #pragma unroll 1
        for (int r = 0; r < 4; ++r) {
          int bi = i0 + wm * 64 + tm * 16 + quad * 4 + r;
          int hh = hb[bi];
          #pragma unroll 1
          for (int tn = 0; tn < 4; ++tn) {
            int jg = j0 + wn * 64 + tn * 16 + r15;
            if (jg < N_ENT) {
              const float* cp1 = ent_f32 + (size_t)hh * DDIM;
              const float* cp2 = rs + (size_t)bi * DDIM;
              const float* ep  = ent_f32 + (size_t)jg * DDIM;
              float man = 0.f;
              #pragma unroll 1
              for (int d = 0; d < DDIM; ++d) man += fabsf(cp1[d] + cp2[d] - ep[d]);
              float s = 100.f / fmaxf(man, 1e-12f);
              ls0 += 0.01f * fminf(s, S_CLAMP);   // same u-unit scale
            }
          }
        }
      }
    }
  }

  // one reduction per block
  float lsum = (ls0 + ls1) + (ls2 + ls3);
  #pragma unroll
  for (int m = 32; m; m >>= 1) lsum += __shfl_xor(lsum, m);
  if (lane == 0) s4[wv] = lsum;
  __syncthreads();
  if (tid == 0)
    partials[id] = (s4[0] + s4[1]) + (s4[2] + s4[3]);
#undef STAGE
#undef LOADBV
#undef LOADA
#undef MFMA16
}

// Single-block deterministic finalize: 1024 threads; thread i takes
// tpart[i] (x -1/(B*N)) and, for i<NGRID, block-partial i (x 100/(B*N));
// double block-reduce, one plain store. No atomics -> no d_out memset.
__global__ __launch_bounds__(1024) void finalize_k(const float* __restrict__ partials,
                                                   const float* __restrict__ tpart,
                                                   float* __restrict__ out) {
  const int tid = threadIdx.x, lane = tid & 63, wv = tid >> 6;
  const double inv = 1.0 / ((double)BSZ * (double)N_ENT);
  double v = (double)tpart[tid] * (-inv);
  if (tid < NGRID) v += (double)partials[tid] * (100.0 * inv);
  #pragma unroll
  for (int m = 32; m; m >>= 1) v += __shfl_xor(v, m);
  __shared__ double sd[16];
  if (lane == 0) sd[wv] = v;
  __syncthreads();
  if (wv == 0) {
    double t = (lane < 16) ? sd[lane] : 0.0;
    #pragma unroll
    for (int m = 8; m; m >>= 1) t += __shfl_xor(t, m);
    if (lane == 0) out[0] = (float)t;
  }
}

extern "C" void kernel_launch(void* const* d_in, const int* in_sizes, int n_in,
                              void* d_out, int out_size, void* d_ws, size_t ws_size,
                              hipStream_t stream) {
  const int*   pos_h = (const int*)d_in[0];
  const int*   pos_t = (const int*)d_in[1];
  const int*   neg_h = (const int*)d_in[2];
  // d_in[3] = neg_t_batch (unused by reference)
  const float* rpos  = (const float*)d_in[4];
  const float* rneg  = (const float*)d_in[5];
  const float* ent   = (const float*)d_in[6];
  const int*   l1    = (const int*)d_in[7];

  char* ws = (char*)d_ws;
  float*          partials = (float*)(ws + OFF_PART);
  float*          tpart    = (float*)(ws + OFF_TPART);
  float*          enorm    = (float*)(ws + OFF_ENORM);
  float*          cnorm    = (float*)(ws + OFF_CNORM);
  unsigned short* c_bf     = (unsigned short*)(ws + OFF_CBF);
  unsigned short* ent_bf   = (unsigned short*)(ws + OFF_EBF);

  prep_k<<<5256, 256, 0, stream>>>(ent, pos_h, pos_t, neg_h, rpos, rneg, l1,
                                   ent_bf, enorm, c_bf, cnorm, tpart);

  main_k<<<NGRID, 256, 0, stream>>>(c_bf, ent_bf, cnorm, enorm, l1,
                                    pos_h, neg_h, rpos, rneg, ent, partials);

  finalize_k<<<1, 1024, 0, stream>>>(partials, tpart, (float*)d_out);
}